// Round 3
// baseline (3887.368 us; speedup 1.0000x reference)
//
#include <hip/hip_runtime.h>
#include <stdint.h>

typedef unsigned int u32;
typedef unsigned long long u64;

#define M_TOTAL  32768          // B*S
#define DLAT     256            // D
#define KD       512            // 2*D (GEMM reduction dim)
#define NCODE    4096           // K codes
#define BM       128
#define BN       64
#define BK       32
#define NKT      (KD / BK)      // 16 K-steps
#define OUT1_OFF 8388608        // B*S*D (f32 elements)
#define OUT_LOSS 16777216
#define OUT_IDX  16777217
#define LOSS_N   16777216.0

// ws layout: [0] double loss_acc; [16] int prev64_flag;
//            [1024] float cn[4096]; [17408] u64 keys[32768]

// ---------------- kernel 0: cnorm (f64) + prev-dtype probe + init ----------------
__global__ __launch_bounds__(256) void vq_prep(
    const float* __restrict__ cb, const u32* __restrict__ prevw,
    float* __restrict__ cn, u64* __restrict__ keys,
    double* __restrict__ loss_acc, int* __restrict__ flag)
{
    const int tid = (int)(blockIdx.x * 256 + threadIdx.x);
    const int ln  = threadIdx.x & 63;
    const int gw  = tid >> 6, nw = (int)((gridDim.x * 256) >> 6);
    for (int row = gw; row < NCODE; row += nw) {
        const float4* p4 = (const float4*)(cb + (size_t)row * KD) + ln * 2;
        float4 a = p4[0], b = p4[1];
        double s = (double)a.x*a.x + (double)a.y*a.y + (double)a.z*a.z + (double)a.w*a.w
                 + (double)b.x*b.x + (double)b.y*b.y + (double)b.z*b.z + (double)b.w*b.w;
        #pragma unroll
        for (int off = 32; off >= 1; off >>= 1) s += __shfl_xor(s, off);
        if (ln == 0) cn[row] = (float)s;
    }
    for (int i = tid; i < M_TOTAL; i += (int)(gridDim.x * 256)) keys[i] = ~0ull;
    if (blockIdx.x == 0 && threadIdx.x < 64) {
        // int64 prev => all high words zero (values in [0,4096)); int32 => ~impossible
        u32 w = prevw[2 * threadIdx.x + 1];
        int allz = __all(w == 0);
        if (threadIdx.x == 0) { *flag = allz; *loss_acc = 0.0; }
    }
}

// ------------- kernel 1: f64-accum distance GEMM + biased argmin -------------
__global__ __launch_bounds__(256) void vq_gemm_argmin(
    const float* __restrict__ zr, const float* __restrict__ zi,
    const void* __restrict__ prevv, const float* __restrict__ cb,
    const float* __restrict__ adj, const float* __restrict__ cn,
    u64* __restrict__ keys, const int* __restrict__ flagp)
{
    __shared__ float As[BM][BK];   // float4-slot XOR-swizzled: slot' = s ^ (row&7)
    __shared__ float Bs[BN][BK];
    __shared__ int prev_s[BM];

    const int tid = threadIdx.x;
    const int tr = tid >> 4, tc = tid & 15;      // 16x16 thread grid
    const int rowbase = blockIdx.y * BM;
    const int colbase = blockIdx.x * BN;
    const int flag64 = *flagp;

    if (tid < BM) {
        int row = rowbase + tid;
        int p = flag64 ? ((const int*)prevv)[2 * row] : ((const int*)prevv)[row];
        prev_s[tid] = p & (NCODE - 1);
    }

    double acc[8][4];                            // rows 16i+tr, cols 16j+tc
    #pragma unroll
    for (int i = 0; i < 8; ++i)
        #pragma unroll
        for (int j = 0; j < 4; ++j) acc[i][j] = 0.0;

    float4* As4 = (float4*)&As[0][0];
    float4* Bs4 = (float4*)&Bs[0][0];

    for (int kt = 0; kt < NKT; ++kt) {
        // issue global loads to regs
        const float* zsrc = (kt < 8) ? zr : zi;
        const int kko = (kt & 7) * BK;           // col offset within the 256-wide half
        const int kgo = kt * BK;                 // col offset within codebook row
        float4 areg[4], breg[2];
        #pragma unroll
        for (int i = 0; i < 4; ++i) {            // A: 128 rows x 8 slots = 1024 float4
            int c = tid + 256 * i, row = c >> 3, s = c & 7;
            areg[i] = *((const float4*)(zsrc + (size_t)(rowbase + row) * DLAT + kko) + s);
        }
        #pragma unroll
        for (int i = 0; i < 2; ++i) {            // B: 64 rows x 8 slots = 512 float4
            int c = tid + 256 * i, row = c >> 3, s = c & 7;
            breg[i] = *((const float4*)(cb + (size_t)(colbase + row) * KD + kgo) + s);
        }
        __syncthreads();                         // all waves done reading prev tile
        #pragma unroll
        for (int i = 0; i < 4; ++i) {
            int c = tid + 256 * i, row = c >> 3, s = c & 7;
            As4[row * 8 + (s ^ (row & 7))] = areg[i];
        }
        #pragma unroll
        for (int i = 0; i < 2; ++i) {
            int c = tid + 256 * i, row = c >> 3, s = c & 7;
            Bs4[row * 8 + (s ^ (row & 7))] = breg[i];
        }
        __syncthreads();                         // tile visible

        #pragma unroll
        for (int s = 0; s < 8; ++s) {
            float4 av[8], bv[4];
            #pragma unroll
            for (int i = 0; i < 8; ++i) {
                int R = 16 * i + tr;
                av[i] = As4[R * 8 + (s ^ (R & 7))];   // (R&7)==(tr&7); 4 distinct banks/wave
            }
            #pragma unroll
            for (int j = 0; j < 4; ++j) {
                int C = 16 * j + tc;
                bv[j] = Bs4[C * 8 + (s ^ (C & 7))];   // 2-way alias max (free)
            }
            #pragma unroll
            for (int i = 0; i < 8; ++i)
                #pragma unroll
                for (int j = 0; j < 4; ++j) {
                    acc[i][j] += (double)av[i].x * bv[j].x;
                    acc[i][j] += (double)av[i].y * bv[j].y;
                    acc[i][j] += (double)av[i].z * bv[j].z;
                    acc[i][j] += (double)av[i].w * bv[j].w;
                }
        }
    }

    // ---- epilogue: score = cn[c] - 2*dot - 0.8*sigmoid(adj[prev,c]); argmin ----
    float cnv[4];
    #pragma unroll
    for (int j = 0; j < 4; ++j) cnv[j] = cn[colbase + 16 * j + tc];

    #pragma unroll
    for (int i = 0; i < 8; ++i) {
        const int R = 16 * i + tr;
        const int p = prev_s[R];
        const float* arow = adj + (size_t)p * NCODE + colbase + tc;
        float bs = 3.0e38f; int bc = 0x7FFFFFFF;
        #pragma unroll
        for (int j = 0; j < 4; ++j) {
            float a  = arow[16 * j];
            float sg = 1.0f / (1.0f + __expf(-a));
            float t  = (float)((double)cnv[j] - 2.0 * acc[i][j]);
            float s  = t - 0.8f * sg;
            int   c  = colbase + 16 * j + tc;
            if (s < bs) { bs = s; bc = c; }          // j ascending → lowest idx on tie
        }
        #pragma unroll
        for (int off = 8; off >= 1; off >>= 1) {     // reduce 16 lanes (same tr) per row
            float s2 = __shfl_xor(bs, off);
            int   c2 = __shfl_xor(bc, off);
            if (s2 < bs || (s2 == bs && c2 < bc)) { bs = s2; bc = c2; }
        }
        if (tc == 0) {
            u32 u = __float_as_uint(bs);
            u = (u & 0x80000000u) ? ~u : (u | 0x80000000u);  // sortable f32
            u64 key = ((u64)u << 32) | (u32)bc;              // tie → lowest col
            atomicMin(&keys[rowbase + R], key);
        }
    }
}

// ------ kernel 2: gather z_q → outputs (f32) + loss (f64 accum) ------
__global__ __launch_bounds__(256) void vq_gather(
    const float* __restrict__ zr, const float* __restrict__ zi,
    const float* __restrict__ cb, const u64* __restrict__ keys,
    float* __restrict__ out, double* __restrict__ loss_acc)
{
    const int ln = threadIdx.x & 63;
    const int gw = (int)((blockIdx.x * 256 + threadIdx.x) >> 6);
    const int nw = (int)((gridDim.x * 256) >> 6);
    double ls = 0.0;
    for (int r = gw; r < M_TOTAL; r += nw) {
        int idx = (int)(u32)(keys[r] & 0xFFFFFFFFull) & (NCODE - 1);
        if (ln == 0) out[OUT_IDX + r] = (float)idx;   // exact integer in f32
        const float4* c4 = (const float4*)(cb + (size_t)idx * KD);
        float4 a = c4[ln * 2], b = c4[ln * 2 + 1];    // elements ln*8 .. ln*8+7
        const float4* z4 = (ln < 32)
            ? (const float4*)(zr + (size_t)r * DLAT) + ln * 2
            : (const float4*)(zi + (size_t)r * DLAT) + (ln - 32) * 2;
        float4 za = z4[0], zb = z4[1];
        float4* o4 = (ln < 32)
            ? (float4*)(out + (size_t)r * DLAT) + ln * 2
            : (float4*)(out + OUT1_OFF + (size_t)r * DLAT) + (ln - 32) * 2;
        o4[0] = a; o4[1] = b;                          // z_q_st == z_q (value-exact)
        double d;
        d = (double)a.x - za.x; ls += d * d;
        d = (double)a.y - za.y; ls += d * d;
        d = (double)a.z - za.z; ls += d * d;
        d = (double)a.w - za.w; ls += d * d;
        d = (double)b.x - zb.x; ls += d * d;
        d = (double)b.y - zb.y; ls += d * d;
        d = (double)b.z - zb.z; ls += d * d;
        d = (double)b.w - zb.w; ls += d * d;
    }
    #pragma unroll
    for (int off = 32; off >= 1; off >>= 1) ls += __shfl_xor(ls, off);
    if (ln == 0) atomicAdd(loss_acc, ls);
}

// ---------------- kernel 3: finalize loss ----------------
__global__ void vq_finish(const double* __restrict__ loss_acc, float* __restrict__ out)
{
    // loss_vq + 0.01*loss_commit == 1.01 * mean((z_q - z)^2)
    out[OUT_LOSS] = (float)(*loss_acc * 1.01 / LOSS_N);
}

extern "C" void kernel_launch(void* const* d_in, const int* in_sizes, int n_in,
                              void* d_out, int out_size, void* d_ws, size_t ws_size,
                              hipStream_t stream)
{
    const float* zr  = (const float*)d_in[0];
    const float* zi  = (const float*)d_in[1];
    const void*  prev = d_in[2];
    const float* cb  = (const float*)d_in[3];
    const float* adj = (const float*)d_in[4];
    float* out = (float*)d_out;

    char* ws = (char*)d_ws;
    double* loss_acc = (double*)ws;                              // 8 B
    int*    flag     = (int*)(ws + 16);                          // 4 B
    float*  cn       = (float*)(ws + 1024);                      // 16 KB f32[4096]
    u64*    keys     = (u64*)(ws + 1024 + 16384);                // 256 KB u64[32768]

    vq_prep<<<64, 256, 0, stream>>>(cb, (const u32*)prev, cn, keys, loss_acc, flag);
    dim3 g1(NCODE / BN, M_TOTAL / BM);                           // 64 x 256 blocks
    vq_gemm_argmin<<<g1, 256, 0, stream>>>(zr, zi, prev, cb, adj, cn, keys, flag);
    vq_gather<<<512, 256, 0, stream>>>(zr, zi, cb, keys, out, loss_acc);
    vq_finish<<<1, 1, 0, stream>>>(loss_acc, out);
}

// Round 4
// 1083.335 us; speedup vs baseline: 3.5883x; 3.5883x over previous
//
#include <hip/hip_runtime.h>
#include <stdint.h>

typedef unsigned short u16;
typedef unsigned int u32;
typedef unsigned long long u64;

#define M_TOTAL  32768          // B*S
#define DLAT     256            // D
#define KD       512            // 2*D
#define NCODE    4096           // K codes
#define BM       128
#define BN       128
#define BK       32
#define NKT      16             // KD/BK
#define OUT1_OFF 8388608        // B*S*D
#define OUT_LOSS 16777216
#define OUT_IDX  16777217
#define LOSS_N   16777216.0
#define TAU      0.8f           // 2x the 11-sigma bf16-noise bound
#define QCAP     512

typedef __attribute__((ext_vector_type(8))) short bf16x8;
typedef __attribute__((ext_vector_type(4))) float f32x4;

__device__ __forceinline__ u16 f2bf(float f) {            // RNE f32->bf16
    union { float f; u32 i; } v; v.f = f;
    return (u16)((v.i + 0x7FFFu + ((v.i >> 16) & 1u)) >> 16);
}
__device__ __forceinline__ u32 pack2(float lo, float hi) {
    return (u32)f2bf(lo) | ((u32)f2bf(hi) << 16);
}
__device__ __forceinline__ u32 sort32(float f) {
    u32 u = __float_as_uint(f);
    return (u & 0x80000000u) ? ~u : (u | 0x80000000u);
}
__device__ __forceinline__ float unsort32(u32 u) {
    u = (u & 0x80000000u) ? (u & 0x7FFFFFFFu) : ~u;
    return __uint_as_float(u);
}
__device__ __forceinline__ u64 sort64(double d) {
    union { double d; u64 u; } v; v.d = d;
    return (v.u >> 63) ? ~v.u : (v.u | 0x8000000000000000ull);
}

// ws layout
#define WS_LOSS   0
#define WS_FLAG   16
#define WS_KEYS   4096          // u64[32768] = 256 KB
#define WS_CND    266240        // double[4096] = 32 KB
#define WS_LMIN   299008        // float[32768*32] = 4 MB
#define WS_RMIN   4493312       // float[32768] = 128 KB

// ---------------- kernel 0: cnorm(f64) + init + prev-dtype probe ----------------
__global__ __launch_bounds__(256) void vq_prep(
    const float* __restrict__ cb, const u32* __restrict__ prevw,
    double* __restrict__ cnd, u64* __restrict__ keys,
    double* __restrict__ loss_acc, int* __restrict__ flag)
{
    const int tid = (int)(blockIdx.x * 256 + threadIdx.x);
    const int ln  = threadIdx.x & 63;
    const int gw  = tid >> 6, nw = (int)((gridDim.x * 256) >> 6);
    for (int row = gw; row < NCODE; row += nw) {
        const float4* p4 = (const float4*)(cb + (size_t)row * KD) + ln * 2;
        float4 a = p4[0], b = p4[1];
        double s = (double)a.x*a.x + (double)a.y*a.y + (double)a.z*a.z + (double)a.w*a.w
                 + (double)b.x*b.x + (double)b.y*b.y + (double)b.z*b.z + (double)b.w*b.w;
        #pragma unroll
        for (int off = 32; off >= 1; off >>= 1) s += __shfl_xor(s, off);
        if (ln == 0) cnd[row] = s;
    }
    for (int i = tid; i < M_TOTAL; i += (int)(gridDim.x * 256)) keys[i] = ~0ull;
    if (blockIdx.x == 0 && threadIdx.x < 64) {
        u32 w = prevw[2 * threadIdx.x + 1];     // int64 -> high words all zero
        int allz = __all(w == 0);
        if (threadIdx.x == 0) { *flag = allz; *loss_acc = 0.0; }
    }
}

// -------- pass kernel: bf16 MFMA approx scores; RESCORE=0 local-min, =1 exact --------
template<int RESCORE>
__global__ __launch_bounds__(256, 2) void vq_pass(
    const float* __restrict__ zr, const float* __restrict__ zi,
    const void* __restrict__ prevv, const float* __restrict__ cb,
    const float* __restrict__ adj, const double* __restrict__ cnd,
    float* __restrict__ localmin, const float* __restrict__ rowmin,
    u64* __restrict__ keys, const int* __restrict__ flagp)
{
    __shared__ u16 As[BM][BK];
    __shared__ u16 Bs[BN][BK];
    __shared__ int prev_s[BM];
    __shared__ u32 lmin_s[BM];
    __shared__ float rmin_s[BM];
    __shared__ u32 q_s[QCAP];
    __shared__ int qcnt;

    const int tid = threadIdx.x;
    const int wv  = tid >> 6, ln = tid & 63;
    const int lhi = ln >> 4, llo = ln & 15;
    const int wm  = wv >> 1, wn = wv & 1;           // 2x2 waves, 64x64 each
    const int rowbase = blockIdx.y * BM;
    const int colbase = blockIdx.x * BN;
    const int flag64 = *flagp;

    if (tid < BM) {
        int p = flag64 ? ((const int*)prevv)[2 * (rowbase + tid)]
                       : ((const int*)prevv)[rowbase + tid];
        prev_s[tid] = p & (NCODE - 1);
        if (RESCORE) rmin_s[tid] = rowmin[rowbase + tid];
        else         lmin_s[tid] = 0xFFFFFFFFu;
    }
    if (RESCORE && tid == 0) qcnt = 0;

    f32x4 acc[4][4];
    #pragma unroll
    for (int m = 0; m < 4; ++m)
        #pragma unroll
        for (int n = 0; n < 4; ++n) acc[m][n] = (f32x4){0.f, 0.f, 0.f, 0.f};

    const int srow = tid >> 1, skh = (tid & 1) * 16;   // staging: row, k-half

    for (int kt = 0; kt < NKT; ++kt) {
        // issue f32 loads (prefetch while LDS still in use)
        const float* zsrc = (kt < 8) ? zr : zi;
        const float* ap = zsrc + (size_t)(rowbase + srow) * DLAT + (kt & 7) * BK + skh;
        const float* bp = cb   + (size_t)(colbase + srow) * KD  + kt * BK + skh;
        float4 a0 = ((const float4*)ap)[0], a1 = ((const float4*)ap)[1];
        float4 a2 = ((const float4*)ap)[2], a3 = ((const float4*)ap)[3];
        float4 b0 = ((const float4*)bp)[0], b1 = ((const float4*)bp)[1];
        float4 b2 = ((const float4*)bp)[2], b3 = ((const float4*)bp)[3];
        __syncthreads();                       // all waves done reading prev tile
        uint4 w0, w1;
        w0.x = pack2(a0.x, a0.y); w0.y = pack2(a0.z, a0.w);
        w0.z = pack2(a1.x, a1.y); w0.w = pack2(a1.z, a1.w);
        w1.x = pack2(a2.x, a2.y); w1.y = pack2(a2.z, a2.w);
        w1.z = pack2(a3.x, a3.y); w1.w = pack2(a3.z, a3.w);
        *(uint4*)&As[srow][skh]     = w0;
        *(uint4*)&As[srow][skh + 8] = w1;
        w0.x = pack2(b0.x, b0.y); w0.y = pack2(b0.z, b0.w);
        w0.z = pack2(b1.x, b1.y); w0.w = pack2(b1.z, b1.w);
        w1.x = pack2(b2.x, b2.y); w1.y = pack2(b2.z, b2.w);
        w1.z = pack2(b3.x, b3.y); w1.w = pack2(b3.z, b3.w);
        *(uint4*)&Bs[srow][skh]     = w0;
        *(uint4*)&Bs[srow][skh + 8] = w1;
        __syncthreads();                       // tile visible

        bf16x8 af[4], bfr[4];
        #pragma unroll
        for (int m = 0; m < 4; ++m)
            af[m] = *(const bf16x8*)&As[wm * 64 + m * 16 + llo][lhi * 8];
        #pragma unroll
        for (int n = 0; n < 4; ++n)
            bfr[n] = *(const bf16x8*)&Bs[wn * 64 + n * 16 + llo][lhi * 8];
        #pragma unroll
        for (int m = 0; m < 4; ++m)
            #pragma unroll
            for (int n = 0; n < 4; ++n)
                acc[m][n] = __builtin_amdgcn_mfma_f32_16x16x32_bf16(
                    af[m], bfr[n], acc[m][n], 0, 0, 0);
    }

    // ---- epilogue: s = cn[c] - 2*dot - 0.8*sigmoid(adj[prev,c]) ----
    float cnv[4];
    #pragma unroll
    for (int n = 0; n < 4; ++n) cnv[n] = (float)cnd[colbase + wn * 64 + n * 16 + llo];

    #pragma unroll
    for (int m = 0; m < 4; ++m) {
        #pragma unroll
        for (int r = 0; r < 4; ++r) {
            const int Rl = wm * 64 + m * 16 + lhi * 4 + r;   // C/D row=(l>>4)*4+reg
            const float* arow = adj + (size_t)prev_s[Rl] * NCODE + colbase + wn * 64 + llo;
            if (RESCORE == 0) {
                float bs = 3.0e38f;
                #pragma unroll
                for (int n = 0; n < 4; ++n) {
                    float sg = 1.0f / (1.0f + __expf(-arow[n * 16]));
                    float s  = cnv[n] - 2.0f * acc[m][n][r] - 0.8f * sg;
                    bs = fminf(bs, s);
                }
                #pragma unroll
                for (int off = 8; off >= 1; off >>= 1)
                    bs = fminf(bs, __shfl_xor(bs, off));     // reduce 16 llo lanes
                if (llo == 0) atomicMin(&lmin_s[Rl], sort32(bs));
            } else {
                const float thr = rmin_s[Rl] + TAU;
                #pragma unroll
                for (int n = 0; n < 4; ++n) {
                    float sg = 1.0f / (1.0f + __expf(-arow[n * 16]));
                    float s  = cnv[n] - 2.0f * acc[m][n][r] - 0.8f * sg;
                    if (s <= thr) {
                        int c = colbase + wn * 64 + n * 16 + llo;
                        int slot = atomicAdd(&qcnt, 1);
                        if (slot < QCAP) q_s[slot] = ((u32)Rl << 12) | (u32)c;
                    }
                }
            }
        }
    }
    __syncthreads();

    if (RESCORE == 0) {
        if (tid < BM)
            localmin[(size_t)(rowbase + tid) * 32 + blockIdx.x] = unsort32(lmin_s[tid]);
    } else {
        const int cnt = (qcnt < QCAP) ? qcnt : QCAP;
        for (int qi = wv; qi < cnt; qi += 4) {               // one wave per candidate
            u32 qv = q_s[qi];
            int Rl = (int)(qv >> 12), c = (int)(qv & 0xFFFu);
            int grow = rowbase + Rl;
            const float* zp = (ln < 32) ? zr + (size_t)grow * DLAT + ln * 8
                                        : zi + (size_t)grow * DLAT + (ln - 32) * 8;
            const float* cp = cb + (size_t)c * KD + ln * 8;
            float4 z0 = ((const float4*)zp)[0], z1 = ((const float4*)zp)[1];
            float4 c0 = ((const float4*)cp)[0], c1 = ((const float4*)cp)[1];
            double d = (double)z0.x*c0.x + (double)z0.y*c0.y
                     + (double)z0.z*c0.z + (double)z0.w*c0.w
                     + (double)z1.x*c1.x + (double)z1.y*c1.y
                     + (double)z1.z*c1.z + (double)z1.w*c1.w;
            #pragma unroll
            for (int off = 32; off >= 1; off >>= 1) d += __shfl_xor(d, off);
            if (ln == 0) {
                double a  = (double)adj[(size_t)prev_s[Rl] * NCODE + c];
                double sg = 1.0 / (1.0 + exp(-a));
                double s  = cnd[c] - 2.0 * d - 0.8 * sg;
                u64 key = (sort64(s) & ~0xFFFull) | (u64)(u32)c;  // tie -> lowest col
                atomicMin(&keys[grow], key);
            }
        }
    }
}

// ---------------- per-row min over 32 colblocks ----------------
__global__ __launch_bounds__(256) void vq_rowmin(
    const float* __restrict__ localmin, float* __restrict__ rowmin)
{
    int r = (int)(blockIdx.x * 256 + threadIdx.x);
    if (r >= M_TOTAL) return;
    const float4* p = (const float4*)(localmin + (size_t)r * 32);
    float m = 3.0e38f;
    #pragma unroll
    for (int i = 0; i < 8; ++i) {
        float4 v = p[i];
        m = fminf(m, fminf(fminf(v.x, v.y), fminf(v.z, v.w)));
    }
    rowmin[r] = m;
}

// ------ gather z_q -> outputs (f32) + loss (f64 accum) ------
__global__ __launch_bounds__(256) void vq_gather(
    const float* __restrict__ zr, const float* __restrict__ zi,
    const float* __restrict__ cb, const u64* __restrict__ keys,
    float* __restrict__ out, double* __restrict__ loss_acc)
{
    const int ln = threadIdx.x & 63;
    const int gw = (int)((blockIdx.x * 256 + threadIdx.x) >> 6);
    const int nw = (int)((gridDim.x * 256) >> 6);
    double ls = 0.0;
    for (int r = gw; r < M_TOTAL; r += nw) {
        int idx = (int)(keys[r] & 0xFFFull);
        if (ln == 0) out[OUT_IDX + r] = (float)idx;
        const float4* c4 = (const float4*)(cb + (size_t)idx * KD);
        float4 a = c4[ln * 2], b = c4[ln * 2 + 1];
        const float4* z4 = (ln < 32)
            ? (const float4*)(zr + (size_t)r * DLAT) + ln * 2
            : (const float4*)(zi + (size_t)r * DLAT) + (ln - 32) * 2;
        float4 za = z4[0], zb = z4[1];
        float4* o4 = (ln < 32)
            ? (float4*)(out + (size_t)r * DLAT) + ln * 2
            : (float4*)(out + OUT1_OFF + (size_t)r * DLAT) + (ln - 32) * 2;
        o4[0] = a; o4[1] = b;
        double d;
        d = (double)a.x - za.x; ls += d * d;
        d = (double)a.y - za.y; ls += d * d;
        d = (double)a.z - za.z; ls += d * d;
        d = (double)a.w - za.w; ls += d * d;
        d = (double)b.x - zb.x; ls += d * d;
        d = (double)b.y - zb.y; ls += d * d;
        d = (double)b.z - zb.z; ls += d * d;
        d = (double)b.w - zb.w; ls += d * d;
    }
    #pragma unroll
    for (int off = 32; off >= 1; off >>= 1) ls += __shfl_xor(ls, off);
    if (ln == 0) atomicAdd(loss_acc, ls);
}

__global__ void vq_finish(const double* __restrict__ loss_acc, float* __restrict__ out)
{
    out[OUT_LOSS] = (float)(*loss_acc * 1.01 / LOSS_N);
}

extern "C" void kernel_launch(void* const* d_in, const int* in_sizes, int n_in,
                              void* d_out, int out_size, void* d_ws, size_t ws_size,
                              hipStream_t stream)
{
    const float* zr  = (const float*)d_in[0];
    const float* zi  = (const float*)d_in[1];
    const void*  prev = d_in[2];
    const float* cb  = (const float*)d_in[3];
    const float* adj = (const float*)d_in[4];
    float* out = (float*)d_out;

    char* ws = (char*)d_ws;
    double* loss_acc = (double*)(ws + WS_LOSS);
    int*    flag     = (int*)(ws + WS_FLAG);
    u64*    keys     = (u64*)(ws + WS_KEYS);
    double* cnd      = (double*)(ws + WS_CND);
    float*  lmin     = (float*)(ws + WS_LMIN);
    float*  rmin     = (float*)(ws + WS_RMIN);

    vq_prep<<<64, 256, 0, stream>>>(cb, (const u32*)prev, cnd, keys, loss_acc, flag);
    dim3 g1(NCODE / BN, M_TOTAL / BM);                       // 32 x 256
    vq_pass<0><<<g1, 256, 0, stream>>>(zr, zi, prev, cb, adj, cnd, lmin, rmin, keys, flag);
    vq_rowmin<<<M_TOTAL / 256, 256, 0, stream>>>(lmin, rmin);
    vq_pass<1><<<g1, 256, 0, stream>>>(zr, zi, prev, cb, adj, cnd, lmin, rmin, keys, flag);
    vq_gather<<<512, 256, 0, stream>>>(zr, zi, cb, keys, out, loss_acc);
    vq_finish<<<1, 1, 0, stream>>>(loss_acc, out);
}